// Round 2
// baseline (153.245 us; speedup 1.0000x reference)
//
#include <hip/hip_runtime.h>
#include <hip/hip_bf16.h>
#include <math.h>

#define G 4
#define T 2048
#define H 1024
#define E 8

typedef float f4 __attribute__((ext_vector_type(4)));
typedef int i4v __attribute__((ext_vector_type(4)));

// ---------------------------------------------------------------------------
// Kernel A: logits = x@W + b (fp64 accumulate), probs + lse^2 to workspace.
// One wave (64 lanes) per token; coalesced float4 loads of the 1024-dim row.
// ---------------------------------------------------------------------------
__global__ __launch_bounds__(256) void router_logits(
    const float* __restrict__ x, const float* __restrict__ W,
    const float* __restrict__ b, float* __restrict__ probs,
    float* __restrict__ lse2) {
  int wave = (int)((blockIdx.x * blockDim.x + threadIdx.x) >> 6);
  int lane = threadIdx.x & 63;
  if (wave >= G * T) return;
  const float* xr = x + (size_t)wave * H;

  double acc0 = 0, acc1 = 0, acc2 = 0, acc3 = 0;
  double acc4 = 0, acc5 = 0, acc6 = 0, acc7 = 0;
#pragma unroll
  for (int j = 0; j < 4; ++j) {
    int hbase = j * 256 + lane * 4;
    f4 xv = *(const f4*)(xr + hbase);
#pragma unroll
    for (int k = 0; k < 4; ++k) {
      const float* wr = W + (size_t)(hbase + k) * 8;
      f4 w0 = *(const f4*)(wr);
      f4 w1 = *(const f4*)(wr + 4);
      double xd = (double)xv[k];
      acc0 += xd * (double)w0[0];
      acc1 += xd * (double)w0[1];
      acc2 += xd * (double)w0[2];
      acc3 += xd * (double)w0[3];
      acc4 += xd * (double)w1[0];
      acc5 += xd * (double)w1[1];
      acc6 += xd * (double)w1[2];
      acc7 += xd * (double)w1[3];
    }
  }
#pragma unroll
  for (int off = 32; off >= 1; off >>= 1) {
    acc0 += __shfl_xor(acc0, off);
    acc1 += __shfl_xor(acc1, off);
    acc2 += __shfl_xor(acc2, off);
    acc3 += __shfl_xor(acc3, off);
    acc4 += __shfl_xor(acc4, off);
    acc5 += __shfl_xor(acc5, off);
    acc6 += __shfl_xor(acc6, off);
    acc7 += __shfl_xor(acc7, off);
  }
  if (lane == 0) {
    double l0 = acc0 + (double)b[0], l1 = acc1 + (double)b[1];
    double l2 = acc2 + (double)b[2], l3 = acc3 + (double)b[3];
    double l4 = acc4 + (double)b[4], l5 = acc5 + (double)b[5];
    double l6 = acc6 + (double)b[6], l7 = acc7 + (double)b[7];
    double m = fmax(fmax(fmax(l0, l1), fmax(l2, l3)),
                    fmax(fmax(l4, l5), fmax(l6, l7)));
    double p0 = exp(l0 - m), p1 = exp(l1 - m), p2 = exp(l2 - m),
           p3 = exp(l3 - m), p4 = exp(l4 - m), p5 = exp(l5 - m),
           p6 = exp(l6 - m), p7 = exp(l7 - m);
    double s = ((p0 + p1) + (p2 + p3)) + ((p4 + p5) + (p6 + p7));
    double inv = 1.0 / s;
    f4 v0 = {(float)(p0 * inv), (float)(p1 * inv), (float)(p2 * inv),
             (float)(p3 * inv)};
    f4 v1 = {(float)(p4 * inv), (float)(p5 * inv), (float)(p6 * inv),
             (float)(p7 * inv)};
    *(f4*)(probs + (size_t)wave * 8) = v0;
    *(f4*)(probs + (size_t)wave * 8 + 4) = v1;
    double lse = m + log(s);
    lse2[wave] = (float)(lse * lse);
  }
}

// ---------------------------------------------------------------------------
// Kernel B: per-(g,e) full bitonic sort of 2048 packed keys in LDS.
// Key = (prob_bits << 32) | ~t  -> descending sort == (value desc, index asc),
// exactly matching jax.lax.top_k tie-breaking. Emits gate/idx padded with
// (0.f, -1) beyond cap_e so the fill kernel needs no capacity logic.
// ---------------------------------------------------------------------------
__global__ __launch_bounds__(256) void topk_sort(
    const float* __restrict__ probs, float* __restrict__ gate,
    int* __restrict__ idx, int max_cap, int ec) {
  __shared__ unsigned long long keys[T];
  int ge = blockIdx.x;  // g*8 + e
  int g = ge >> 3, e = ge & 7;
  int tid = threadIdx.x;

  for (int t = tid; t < T; t += 256) {
    float p = probs[((size_t)g * T + t) * 8 + e];
    unsigned int bits = __float_as_uint(p);  // probs >= 0 -> monotonic as uint
    keys[t] = ((unsigned long long)bits << 32) | (unsigned int)(~t);
  }
  for (unsigned k = 2; k <= T; k <<= 1) {
    for (unsigned j = k >> 1; j > 0; j >>= 1) {
      __syncthreads();
      for (unsigned i = tid; i < T; i += 256) {
        unsigned ixj = i ^ j;
        if (ixj > i) {
          unsigned long long a = keys[i], c = keys[ixj];
          bool desc = ((i & k) == 0);
          if (desc ? (a < c) : (a > c)) {
            keys[i] = c;
            keys[ixj] = a;
          }
        }
      }
    }
  }
  __syncthreads();

  const double factors[8] = {0.5, 0.75, 1.0, 1.0, 1.25, 1.25, 1.5, 1.5};
  int cap = (int)((double)ec * factors[e]);
  for (int c = tid; c < max_cap; c += 256) {
    size_t o = (size_t)ge * max_cap + c;
    if (c < cap) {
      unsigned long long kk = keys[c];
      gate[o] = __uint_as_float((unsigned)(kk >> 32));
      idx[o] = (int)(~(unsigned)kk);
    } else {
      gate[o] = 0.0f;
      idx[o] = -1;  // never equals a token id in [0, T)
    }
  }
}

// ---------------------------------------------------------------------------
// Kernel C: fill dispatch (float 0/1) and combine arrays, 1 float4 of each
// per thread-iter, nontemporal stores. Block 0 also reduces lse^2 -> z_loss
// (deterministic tree) and writes the two trailing scalars.
// ---------------------------------------------------------------------------
template <int MC4S>
__global__ __launch_bounds__(256) void fill_out(
    const float* __restrict__ gate, const int* __restrict__ idx,
    const float* __restrict__ lse2, float* __restrict__ out, unsigned n4,
    unsigned mc4_rt) {
  const unsigned mc4 = MC4S ? (unsigned)MC4S : mc4_rt;
  unsigned tid = threadIdx.x;

  if (blockIdx.x == 0) {
    __shared__ double red[256];
    double s = 0.0;
    for (int i = tid; i < G * T; i += 256) s += (double)lse2[i];
    red[tid] = s;
    __syncthreads();
    for (int off = 128; off > 0; off >>= 1) {
      if ((int)tid < off) red[tid] += red[tid + off];
      __syncthreads();
    }
    if (tid == 0) {
      size_t base = (size_t)n4 * 8;        // = 2 * total elements per array
      out[base] = 0.0f;                    // auxiliary_loss
      out[base + 1] = (float)(red[0] / (double)(G * T));  // z_loss
    }
  }

  f4* outD = (f4*)out;
  f4* outC = outD + n4;
  const f4* gate4 = (const f4*)gate;
  const i4v* idx4 = (const i4v*)idx;
  unsigned stride = gridDim.x * 256u;
  for (unsigned i = blockIdx.x * 256u + tid; i < n4; i += stride) {
    unsigned c4 = i % mc4;
    unsigned rem = i / mc4;
    unsigned t = rem & (T - 1);
    unsigned ge = rem >> 11;  // / T
    f4 gv = gate4[ge * mc4 + c4];
    i4v iv = idx4[ge * mc4 + c4];
    f4 dv;
    dv.x = (iv.x == (int)t) ? 1.0f : 0.0f;
    dv.y = (iv.y == (int)t) ? 1.0f : 0.0f;
    dv.z = (iv.z == (int)t) ? 1.0f : 0.0f;
    dv.w = (iv.w == (int)t) ? 1.0f : 0.0f;
    __builtin_nontemporal_store(dv, &outD[i]);
    __builtin_nontemporal_store(gv, &outC[i]);
  }
}

extern "C" void kernel_launch(void* const* d_in, const int* in_sizes, int n_in,
                              void* d_out, int out_size, void* d_ws,
                              size_t ws_size, hipStream_t stream) {
  const float* x = (const float*)d_in[0];
  const float* W = (const float*)d_in[1];
  const float* b = (const float*)d_in[2];

  // Derive max_cap from out_size: out = 2*G*E*T*max_cap + 2 scalars.
  long long body = (long long)out_size - 2;
  int max_cap = (int)(body / (2LL * G * E * T));  // 384 for ec=256
  if (max_cap <= 0) return;
  int ec = (2 * max_cap) / 3;  // max factor is 1.5

  float* ws = (float*)d_ws;
  float* probs = ws;                   // G*T*E   = 65536 floats
  float* lse2 = ws + (size_t)G * T * E;           // 8192 floats
  float* gate = lse2 + (size_t)G * T;             // G*E*max_cap floats
  int* idx = (int*)(gate + (size_t)G * E * max_cap);

  router_logits<<<(G * T) / 4, 256, 0, stream>>>(x, W, b, probs, lse2);
  topk_sort<<<G * E, 256, 0, stream>>>(probs, gate, idx, max_cap, ec);

  unsigned n4 = (unsigned)((long long)G * E * T * max_cap / 4);
  int blocks = 6144;
  if (max_cap == 384) {
    fill_out<96><<<blocks, 256, 0, stream>>>(gate, idx, lse2, (float*)d_out,
                                             n4, 96u);
  } else {
    fill_out<0><<<blocks, 256, 0, stream>>>(gate, idx, lse2, (float*)d_out, n4,
                                            (unsigned)(max_cap / 4));
  }
}

// Round 3
// 86.547 us; speedup vs baseline: 1.7707x; 1.7707x over previous
//
#include <hip/hip_runtime.h>
#include <hip/hip_bf16.h>
#include <math.h>

#define G 4
#define T 2048
#define H 1024
#define E 8

typedef float f4 __attribute__((ext_vector_type(4)));
typedef int i4v __attribute__((ext_vector_type(4)));

// ---------------------------------------------------------------------------
// Kernel A: logits = x@W + b (fp64 accumulate), probs + lse^2 to workspace.
// One wave (64 lanes) per token; coalesced float4 loads of the 1024-dim row.
// NUMERIC PATH IS FROZEN: absmax=0.0 vs reference in round 2 — top-k ordering
// depends on exact prob bits, so fp64 accumulate + fp64 softmax stays.
// ---------------------------------------------------------------------------
__global__ __launch_bounds__(256) void router_logits(
    const float* __restrict__ x, const float* __restrict__ W,
    const float* __restrict__ b, float* __restrict__ probs,
    float* __restrict__ lse2) {
  int wave = (int)((blockIdx.x * blockDim.x + threadIdx.x) >> 6);
  int lane = threadIdx.x & 63;
  if (wave >= G * T) return;
  const float* xr = x + (size_t)wave * H;

  double acc0 = 0, acc1 = 0, acc2 = 0, acc3 = 0;
  double acc4 = 0, acc5 = 0, acc6 = 0, acc7 = 0;
#pragma unroll
  for (int j = 0; j < 4; ++j) {
    int hbase = j * 256 + lane * 4;
    f4 xv = *(const f4*)(xr + hbase);
#pragma unroll
    for (int k = 0; k < 4; ++k) {
      const float* wr = W + (size_t)(hbase + k) * 8;
      f4 w0 = *(const f4*)(wr);
      f4 w1 = *(const f4*)(wr + 4);
      double xd = (double)xv[k];
      acc0 += xd * (double)w0[0];
      acc1 += xd * (double)w0[1];
      acc2 += xd * (double)w0[2];
      acc3 += xd * (double)w0[3];
      acc4 += xd * (double)w1[0];
      acc5 += xd * (double)w1[1];
      acc6 += xd * (double)w1[2];
      acc7 += xd * (double)w1[3];
    }
  }
#pragma unroll
  for (int off = 32; off >= 1; off >>= 1) {
    acc0 += __shfl_xor(acc0, off);
    acc1 += __shfl_xor(acc1, off);
    acc2 += __shfl_xor(acc2, off);
    acc3 += __shfl_xor(acc3, off);
    acc4 += __shfl_xor(acc4, off);
    acc5 += __shfl_xor(acc5, off);
    acc6 += __shfl_xor(acc6, off);
    acc7 += __shfl_xor(acc7, off);
  }
  if (lane == 0) {
    double l0 = acc0 + (double)b[0], l1 = acc1 + (double)b[1];
    double l2 = acc2 + (double)b[2], l3 = acc3 + (double)b[3];
    double l4 = acc4 + (double)b[4], l5 = acc5 + (double)b[5];
    double l6 = acc6 + (double)b[6], l7 = acc7 + (double)b[7];
    double m = fmax(fmax(fmax(l0, l1), fmax(l2, l3)),
                    fmax(fmax(l4, l5), fmax(l6, l7)));
    double p0 = exp(l0 - m), p1 = exp(l1 - m), p2 = exp(l2 - m),
           p3 = exp(l3 - m), p4 = exp(l4 - m), p5 = exp(l5 - m),
           p6 = exp(l6 - m), p7 = exp(l7 - m);
    double s = ((p0 + p1) + (p2 + p3)) + ((p4 + p5) + (p6 + p7));
    double inv = 1.0 / s;
    f4 v0 = {(float)(p0 * inv), (float)(p1 * inv), (float)(p2 * inv),
             (float)(p3 * inv)};
    f4 v1 = {(float)(p4 * inv), (float)(p5 * inv), (float)(p6 * inv),
             (float)(p7 * inv)};
    *(f4*)(probs + (size_t)wave * 8) = v0;
    *(f4*)(probs + (size_t)wave * 8 + 4) = v1;
    double lse = m + log(s);
    lse2[wave] = (float)(lse * lse);
  }
}

// ---------------------------------------------------------------------------
// Kernel B: per-(g,e) full bitonic sort of 2048 packed keys in LDS.
// 1024 threads, exact-pair indexing: each thread owns exactly one
// compare-exchange per phase (66 phases total). Key = (prob_bits<<32) | ~t
// -> descending sort == (value desc, index asc) == jax.lax.top_k order.
// ---------------------------------------------------------------------------
__global__ __launch_bounds__(1024) void topk_sort(
    const float* __restrict__ probs, float* __restrict__ gate,
    int* __restrict__ idx, int max_cap, int ec) {
  __shared__ unsigned long long keys[T];
  int ge = blockIdx.x;  // g*8 + e
  int g = ge >> 3, e = ge & 7;
  unsigned tid = threadIdx.x;

  for (int t = tid; t < T; t += 1024) {
    float p = probs[((size_t)g * T + t) * 8 + e];
    unsigned int bits = __float_as_uint(p);  // probs >= 0 -> monotonic as uint
    keys[t] = ((unsigned long long)bits << 32) | (unsigned int)(~t);
  }
  __syncthreads();
  for (unsigned k = 2; k <= T; k <<= 1) {
    for (unsigned j = k >> 1; j > 0; j >>= 1) {
      // exactly T/2 = 1024 pairs; thread p owns pair (i, i|j), i|j > i
      unsigned i = ((tid & ~(j - 1)) << 1) | (tid & (j - 1));
      unsigned ixj = i | j;
      unsigned long long a = keys[i], c = keys[ixj];
      bool desc = ((i & k) == 0);
      if (desc ? (a < c) : (a > c)) {
        keys[i] = c;
        keys[ixj] = a;
      }
      __syncthreads();
    }
  }

  const double factors[8] = {0.5, 0.75, 1.0, 1.0, 1.25, 1.25, 1.5, 1.5};
  int cap = (int)((double)ec * factors[e]);
  for (int c = tid; c < max_cap; c += 1024) {
    size_t o = (size_t)ge * max_cap + c;
    if (c < cap) {
      unsigned long long kk = keys[c];
      gate[o] = __uint_as_float((unsigned)(kk >> 32));
      idx[o] = (int)(~(unsigned)kk);
    } else {
      gate[o] = 0.0f;
      idx[o] = -1;  // never equals a token id in [0, T)
    }
  }
}

// ---------------------------------------------------------------------------
// Kernel C: fill dispatch (float 0/1) and combine arrays, 1 float4 of each
// per thread-iter, PLAIN stores (harness fillBuffer evidence: plain streaming
// stores reach ~7 TB/s through L2; nt unproven on gfx950). Block 0 also
// reduces lse^2 -> z_loss and writes the two trailing scalars.
// ---------------------------------------------------------------------------
template <int MC4S>
__global__ __launch_bounds__(256) void fill_out(
    const float* __restrict__ gate, const int* __restrict__ idx,
    const float* __restrict__ lse2, float* __restrict__ out, unsigned n4,
    unsigned mc4_rt) {
  const unsigned mc4 = MC4S ? (unsigned)MC4S : mc4_rt;
  unsigned tid = threadIdx.x;

  if (blockIdx.x == 0) {
    __shared__ double red[256];
    double s = 0.0;
    for (int i = tid; i < G * T; i += 256) s += (double)lse2[i];
    red[tid] = s;
    __syncthreads();
    for (int off = 128; off > 0; off >>= 1) {
      if ((int)tid < off) red[tid] += red[tid + off];
      __syncthreads();
    }
    if (tid == 0) {
      size_t base = (size_t)n4 * 8;        // = 2 * total elements per array
      out[base] = 0.0f;                    // auxiliary_loss
      out[base + 1] = (float)(red[0] / (double)(G * T));  // z_loss
    }
  }

  f4* outD = (f4*)out;
  f4* outC = outD + n4;
  const f4* gate4 = (const f4*)gate;
  const i4v* idx4 = (const i4v*)idx;
  unsigned stride = gridDim.x * 256u;
  for (unsigned i = blockIdx.x * 256u + tid; i < n4; i += stride) {
    unsigned c4 = i % mc4;
    unsigned rem = i / mc4;
    unsigned t = rem & (T - 1);
    unsigned ge = rem >> 11;  // / T
    f4 gv = gate4[ge * mc4 + c4];
    i4v iv = idx4[ge * mc4 + c4];
    f4 dv;
    dv.x = (iv.x == (int)t) ? 1.0f : 0.0f;
    dv.y = (iv.y == (int)t) ? 1.0f : 0.0f;
    dv.z = (iv.z == (int)t) ? 1.0f : 0.0f;
    dv.w = (iv.w == (int)t) ? 1.0f : 0.0f;
    outD[i] = dv;
    outC[i] = gv;
  }
}

extern "C" void kernel_launch(void* const* d_in, const int* in_sizes, int n_in,
                              void* d_out, int out_size, void* d_ws,
                              size_t ws_size, hipStream_t stream) {
  const float* x = (const float*)d_in[0];
  const float* W = (const float*)d_in[1];
  const float* b = (const float*)d_in[2];

  // Derive max_cap from out_size: out = 2*G*E*T*max_cap + 2 scalars.
  long long body = (long long)out_size - 2;
  int max_cap = (int)(body / (2LL * G * E * T));  // 384 for ec=256
  if (max_cap <= 0) return;
  int ec = (2 * max_cap) / 3;  // max factor is 1.5

  float* ws = (float*)d_ws;
  float* probs = ws;                   // G*T*E   = 65536 floats
  float* lse2 = ws + (size_t)G * T * E;           // 8192 floats
  float* gate = lse2 + (size_t)G * T;             // G*E*max_cap floats
  int* idx = (int*)(gate + (size_t)G * E * max_cap);

  router_logits<<<(G * T) / 4, 256, 0, stream>>>(x, W, b, probs, lse2);
  topk_sort<<<G * E, 1024, 0, stream>>>(probs, gate, idx, max_cap, ec);

  unsigned n4 = (unsigned)((long long)G * E * T * max_cap / 4);
  int blocks = 6144;
  if (max_cap == 384) {
    fill_out<96><<<blocks, 256, 0, stream>>>(gate, idx, lse2, (float*)d_out,
                                             n4, 96u);
  } else {
    fill_out<0><<<blocks, 256, 0, stream>>>(gate, idx, lse2, (float*)d_out, n4,
                                            (unsigned)(max_cap / 4));
  }
}

// Round 4
// 78.654 us; speedup vs baseline: 1.9484x; 1.1004x over previous
//
#include <hip/hip_runtime.h>
#include <hip/hip_bf16.h>
#include <math.h>

#define G 4
#define T 2048
#define H 1024
#define E 8
#define NSORT (G * E)  // 32 sort blocks

typedef float f4 __attribute__((ext_vector_type(4)));

// ---------------------------------------------------------------------------
// Kernel A: logits = x@W + b (fp64 accumulate), probs + lse^2 to workspace.
// One wave per token; coalesced float4 loads. NUMERIC PATH FROZEN (absmax=0.0
// in rounds 2-3: top-k ordering depends on exact prob bits).
// ---------------------------------------------------------------------------
__global__ __launch_bounds__(256) void router_logits(
    const float* __restrict__ x, const float* __restrict__ W,
    const float* __restrict__ b, float* __restrict__ probs,
    float* __restrict__ lse2) {
  int wave = (int)((blockIdx.x * blockDim.x + threadIdx.x) >> 6);
  int lane = threadIdx.x & 63;
  if (wave >= G * T) return;
  const float* xr = x + (size_t)wave * H;

  double acc0 = 0, acc1 = 0, acc2 = 0, acc3 = 0;
  double acc4 = 0, acc5 = 0, acc6 = 0, acc7 = 0;
#pragma unroll
  for (int j = 0; j < 4; ++j) {
    int hbase = j * 256 + lane * 4;
    f4 xv = *(const f4*)(xr + hbase);
#pragma unroll
    for (int k = 0; k < 4; ++k) {
      const float* wr = W + (size_t)(hbase + k) * 8;
      f4 w0 = *(const f4*)(wr);
      f4 w1 = *(const f4*)(wr + 4);
      double xd = (double)xv[k];
      acc0 += xd * (double)w0[0];
      acc1 += xd * (double)w0[1];
      acc2 += xd * (double)w0[2];
      acc3 += xd * (double)w0[3];
      acc4 += xd * (double)w1[0];
      acc5 += xd * (double)w1[1];
      acc6 += xd * (double)w1[2];
      acc7 += xd * (double)w1[3];
    }
  }
#pragma unroll
  for (int off = 32; off >= 1; off >>= 1) {
    acc0 += __shfl_xor(acc0, off);
    acc1 += __shfl_xor(acc1, off);
    acc2 += __shfl_xor(acc2, off);
    acc3 += __shfl_xor(acc3, off);
    acc4 += __shfl_xor(acc4, off);
    acc5 += __shfl_xor(acc5, off);
    acc6 += __shfl_xor(acc6, off);
    acc7 += __shfl_xor(acc7, off);
  }
  if (lane == 0) {
    double l0 = acc0 + (double)b[0], l1 = acc1 + (double)b[1];
    double l2 = acc2 + (double)b[2], l3 = acc3 + (double)b[3];
    double l4 = acc4 + (double)b[4], l5 = acc5 + (double)b[5];
    double l6 = acc6 + (double)b[6], l7 = acc7 + (double)b[7];
    double m = fmax(fmax(fmax(l0, l1), fmax(l2, l3)),
                    fmax(fmax(l4, l5), fmax(l6, l7)));
    double p0 = exp(l0 - m), p1 = exp(l1 - m), p2 = exp(l2 - m),
           p3 = exp(l3 - m), p4 = exp(l4 - m), p5 = exp(l5 - m),
           p6 = exp(l6 - m), p7 = exp(l7 - m);
    double s = ((p0 + p1) + (p2 + p3)) + ((p4 + p5) + (p6 + p7));
    double inv = 1.0 / s;
    f4 v0 = {(float)(p0 * inv), (float)(p1 * inv), (float)(p2 * inv),
             (float)(p3 * inv)};
    f4 v1 = {(float)(p4 * inv), (float)(p5 * inv), (float)(p6 * inv),
             (float)(p7 * inv)};
    *(f4*)(probs + (size_t)wave * 8) = v0;
    *(f4*)(probs + (size_t)wave * 8 + 4) = v1;
    double lse = m + log(s);
    lse2[wave] = (float)(lse * lse);
  }
}

// ---------------------------------------------------------------------------
// Kernel B (FUSED): blocks [0,32) = per-(g,e) bitonic sort (latency-bound,
// 32 CUs); blocks [32,..) = zero-fill of the dispatch half (store-bound,
// remaining 224 CUs). Sort blocks are issued first. The zero-fill depends on
// nothing, so it rides for free under the sort's barrier chain.
// ---------------------------------------------------------------------------
__global__ __launch_bounds__(1024) void sort_and_zero(
    const float* __restrict__ probs, float* __restrict__ gate,
    int* __restrict__ idx, float* __restrict__ out, unsigned n4d, int max_cap,
    int ec) {
  __shared__ unsigned long long keys[T];
  unsigned tid = threadIdx.x;
  unsigned bid = blockIdx.x;

  if (bid < NSORT) {
    int g = bid >> 3, e = bid & 7;
    for (int t = tid; t < T; t += 1024) {
      float p = probs[((size_t)g * T + t) * 8 + e];
      unsigned int bits = __float_as_uint(p);  // probs>=0 -> monotonic as uint
      keys[t] = ((unsigned long long)bits << 32) | (unsigned int)(~t);
    }
    __syncthreads();
    for (unsigned k = 2; k <= T; k <<= 1) {
      for (unsigned j = k >> 1; j > 0; j >>= 1) {
        unsigned i = ((tid & ~(j - 1)) << 1) | (tid & (j - 1));
        unsigned ixj = i | j;
        unsigned long long a = keys[i], c = keys[ixj];
        bool desc = ((i & k) == 0);
        if (desc ? (a < c) : (a > c)) {
          keys[i] = c;
          keys[ixj] = a;
        }
        __syncthreads();
      }
    }
    const double factors[8] = {0.5, 0.75, 1.0, 1.0, 1.25, 1.25, 1.5, 1.5};
    int cap = (int)((double)ec * factors[e]);
    for (int c = tid; c < max_cap; c += 1024) {
      size_t o = (size_t)bid * max_cap + c;
      if (c < cap) {
        unsigned long long kk = keys[c];
        gate[o] = __uint_as_float((unsigned)(kk >> 32));
        idx[o] = (int)(~(unsigned)kk);
      } else {
        gate[o] = 0.0f;
        idx[o] = -1;
      }
    }
  } else {
    f4* outD = (f4*)out;
    f4 z = {0.0f, 0.0f, 0.0f, 0.0f};
    unsigned stride = (gridDim.x - NSORT) * 1024u;
    for (unsigned i = (bid - NSORT) * 1024u + tid; i < n4d; i += stride)
      outD[i] = z;
  }
}

// ---------------------------------------------------------------------------
// Kernel C (FUSED): block 0 = z-loss reduce + trailing scalars;
// blocks [1, 1+SCB) = scatter the ~8704 ones into the (pre-zeroed) dispatch
// half; remaining blocks = combine broadcast-fill (gate reads are 48 KB,
// L2-resident; pure f4 store stream).
// ---------------------------------------------------------------------------
template <int MC4S>
__global__ __launch_bounds__(256) void scatter_and_combine(
    const float* __restrict__ gate, const int* __restrict__ idx,
    const float* __restrict__ lse2, float* __restrict__ out, unsigned n4d,
    unsigned mc4_rt, int max_cap, unsigned scb) {
  const unsigned mc4 = MC4S ? (unsigned)MC4S : mc4_rt;
  unsigned tid = threadIdx.x;
  unsigned bid = blockIdx.x;

  if (bid == 0) {
    __shared__ double red[256];
    double s = 0.0;
    for (int i = tid; i < G * T; i += 256) s += (double)lse2[i];
    red[tid] = s;
    __syncthreads();
    for (int off = 128; off > 0; off >>= 1) {
      if ((int)tid < off) red[tid] += red[tid + off];
      __syncthreads();
    }
    if (tid == 0) {
      size_t ne = (size_t)n4d * 4;  // elements per array
      out[2 * ne] = 0.0f;           // auxiliary_loss
      out[2 * ne + 1] = (float)(red[0] / (double)(G * T));  // z_loss
    }
    return;
  }
  if (bid <= scb) {
    unsigned s = (bid - 1) * 256u + tid;
    if (s < (unsigned)(G * E) * (unsigned)max_cap) {
      unsigned ge = s / (unsigned)max_cap;
      unsigned c = s - ge * (unsigned)max_cap;
      int t = idx[s];
      if (t >= 0)
        out[((size_t)ge * T + t) * (unsigned)max_cap + c] = 1.0f;
    }
    return;
  }

  f4* outC = (f4*)out + n4d;  // combine half
  const f4* gate4 = (const f4*)gate;
  unsigned fb = bid - 1 - scb;
  unsigned nfb = gridDim.x - 1 - scb;
  unsigned stride = nfb * 256u;
  for (unsigned i = fb * 256u + tid; i < n4d; i += stride) {
    unsigned c4 = i % mc4;
    unsigned rem = i / mc4;
    unsigned ge = rem >> 11;  // / T
    outC[i] = gate4[ge * mc4 + c4];
  }
}

extern "C" void kernel_launch(void* const* d_in, const int* in_sizes, int n_in,
                              void* d_out, int out_size, void* d_ws,
                              size_t ws_size, hipStream_t stream) {
  const float* x = (const float*)d_in[0];
  const float* W = (const float*)d_in[1];
  const float* b = (const float*)d_in[2];

  // Derive max_cap from out_size: out = 2*G*E*T*max_cap + 2 scalars.
  long long body = (long long)out_size - 2;
  int max_cap = (int)(body / (2LL * G * E * T));  // 384 for ec=256
  if (max_cap <= 0) return;
  int ec = (2 * max_cap) / 3;  // max factor is 1.5

  float* ws = (float*)d_ws;
  float* probs = ws;                    // G*T*E = 65536 floats
  float* lse2 = ws + (size_t)G * T * E; // 8192 floats
  float* gate = lse2 + (size_t)G * T;   // G*E*max_cap floats
  int* idx = (int*)(gate + (size_t)G * E * max_cap);

  unsigned n4d = (unsigned)((long long)G * E * T * max_cap / 4);  // per array
  unsigned scb = (unsigned)((G * E * max_cap + 255) / 256);       // 192

  router_logits<<<(G * T) / 4, 256, 0, stream>>>(x, W, b, probs, lse2);
  sort_and_zero<<<NSORT + 2048, 1024, 0, stream>>>(probs, gate, idx,
                                                   (float*)d_out, n4d, max_cap,
                                                   ec);
  int blocks = 6144;
  if (max_cap == 384) {
    scatter_and_combine<96><<<blocks, 256, 0, stream>>>(
        gate, idx, lse2, (float*)d_out, n4d, 96u, max_cap, scb);
  } else {
    scatter_and_combine<0><<<blocks, 256, 0, stream>>>(
        gate, idx, lse2, (float*)d_out, n4d, (unsigned)(max_cap / 4), max_cap,
        scb);
  }
}